// Round 4
// baseline (986.483 us; speedup 1.0000x reference)
//
#include <hip/hip_runtime.h>

#define Bsz  256
#define Tlen 2048
#define Hdim 128

typedef __fp16 hf2 __attribute__((ext_vector_type(2)));
typedef __fp16 hf8 __attribute__((ext_vector_type(8)));
typedef float  f32x4 __attribute__((ext_vector_type(4)));

// Raw-HW transcendentals (VOP1, ~1 ulp). R12-verified win.
__device__ __forceinline__ float fexp2_(float x) {
    float r; asm("v_exp_f32 %0, %1" : "=v"(r) : "v"(x)); return r;
}
__device__ __forceinline__ float frcp_(float x) {
    float r; asm("v_rcp_f32 %0, %1" : "=v"(r) : "v"(x)); return r;
}

// sum over the 16 lanes of each DPP row via rotate-accumulate (pure VALU,
// no LDS pipe -- the R24 shuffle trap used ds_swizzle/bpermute).
// ROW_ROR:n dpp_ctrl = 0x120 | n.
__device__ __forceinline__ float row16_ror_add(float v, int ctrl_n) {
    int vi = __builtin_bit_cast(int, v);
    int ri;
    switch (ctrl_n) {
        case 8: ri = __builtin_amdgcn_update_dpp(0, vi, 0x128, 0xf, 0xf, true); break;
        case 4: ri = __builtin_amdgcn_update_dpp(0, vi, 0x124, 0xf, 0xf, true); break;
        case 2: ri = __builtin_amdgcn_update_dpp(0, vi, 0x122, 0xf, 0xf, true); break;
        default:ri = __builtin_amdgcn_update_dpp(0, vi, 0x121, 0xf, 0xf, true); break;
    }
    return v + __builtin_bit_cast(float, ri);
}
__device__ __forceinline__ float row16_sum(float v) {
    v = row16_ror_add(v, 8);
    v = row16_ror_add(v, 4);
    v = row16_ror_add(v, 2);
    v = row16_ror_add(v, 1);
    return v;   // every lane in the 16-lane row holds the row sum
}

// pack 8 consecutive f32 into a v8f16 MFMA fragment slice
__device__ __forceinline__ hf8 pack8(const float* p) {
    union { hf2 h2[4]; hf8 h8; } u;
    u.h2[0] = __builtin_amdgcn_cvt_pkrtz(p[0], p[1]);
    u.h2[1] = __builtin_amdgcn_cvt_pkrtz(p[2], p[3]);
    u.h2[2] = __builtin_amdgcn_cvt_pkrtz(p[4], p[5]);
    u.h2[3] = __builtin_amdgcn_cvt_pkrtz(p[6], p[7]);
    return u.h8;
}
__device__ __forceinline__ hf8 bch8(float4 v) { return __builtin_bit_cast(hf8, v); }

#define MFMA(D, A, B) D = __builtin_amdgcn_mfma_f32_16x16x32_f16(A, B, D, 0, 0, 0)

struct Smem {
    float  x[Tlen];       // staged input row
    float  xh[Tlen];      // staged xh outputs
    __fp16 h[2][Hdim];    // double-buffered hidden state (f16)
    float  fcp[2][8];     // double-buffered per-wave fc partials
};

// grid = 256 blocks (1 batch row each), block = 512 threads (8 waves).
// R27 = R26 minus the D3 (fc) MFMA chain: fc computed ONE STEP EARLY.
// Post-mortems: R24 (fc->VALU chain in-step) -21%: serial fma_mix+shuffle
// appendage. R26 (VALU diet) flat: per-lane VALU not critical. Model: step
// = A-load(120) + MFMA drain(560 = 2 waves x 16 x 17.5) + tail + barrier.
// MFMA drain is the largest critical-path term -> cut insts 16 -> 12:
//  - At end of step t-1 each lane holds hn (unit ug) IN REGISTERS. fc
//    partial = wfc[ug]*hn reduced over the 16-lane m-group via DPP
//    row_ror adds (8 VALU insts, no LDS pipe); lane 0 writes the wave
//    partial to double-buffered fcp[(t+1)&1][wave] before the existing
//    barrier. No extra barrier.
//  - Step start: 2 uniform ds_read_b128 of fcp (broadcast; latency
//    overlaps the A-reads) + 8-term tree sum + bfc -> xh ready ~150 cyc
//    in, BEFORE any MFMA result. cur/pr/pz/an off the MFMA dependency.
//  - Numerics: fc now f32 hn x f32 wfc (reference is f32 h) -- closer
//    than the old f16 MFMA path; recurrence error still f16-h bound.
//  - Bf fragments + C_F deleted (-16 AGPR).
// Everything else: R21/R25 champion structure (uniform-A, weights
// MFMA-only/AGPR-native, one barrier/step, LDS-staged outputs, 8 waves /
// 2 per SIMD; R16/R22/R23/R24 perturbations all regressed).
// Layouts (R18-R21 HW-verified): B: lane l reg j = W[tile*16+(l&15)]
// [c*32+(l>>4)*8+j]; D: col = lane&15, reg 0 valid on all lanes (uniform A).
__global__ __launch_bounds__(512, 2)
void rnn_imp_kernel(const float* __restrict__ x,     // [B, T] (I=1)
                    const float* __restrict__ Wih,   // [384]
                    const float* __restrict__ Whh,   // [384, 128] gate-major (r,z,n)
                    const float* __restrict__ bih,   // [384]
                    const float* __restrict__ bhh,   // [384]
                    const float* __restrict__ Wfc,   // [128]
                    const float* __restrict__ bfc,   // [1]
                    float* __restrict__ out_newin,   // [T, B]
                    float* __restrict__ out_pred)    // [B, T-1]
{
    __shared__ __align__(128) Smem sm;

    const int tid  = threadIdx.x;
    const int b    = blockIdx.x;
    const int wave = tid >> 6;
    const int lane = tid & 63;
    const int m    = lane & 15;      // B/D column = unit-in-tile
    const int q    = lane >> 4;      // k-subchunk

    // stage x row (coalesced)
    for (int i = tid; i < Tlen; i += 512) sm.x[i] = x[b * Tlen + i];

    // ---- B fragments: W^T tiles (consumed only by MFMA -> AGPR-native) ----
    const int r0 = wave * 16 + m;            // unit row, gate r
    const int r1 = r0 + 128;                 // gate z
    const int r2 = r0 + 256;                 // gate n
    const int ko = q * 8;
    hf8 Br0, Br1, Br2, Br3, Bz0, Bz1, Bz2, Bz3, Bn0, Bn1, Bn2, Bn3;
    Br0 = pack8(Whh + r0 * Hdim + 0  + ko);  Br1 = pack8(Whh + r0 * Hdim + 32 + ko);
    Br2 = pack8(Whh + r0 * Hdim + 64 + ko);  Br3 = pack8(Whh + r0 * Hdim + 96 + ko);
    Bz0 = pack8(Whh + r1 * Hdim + 0  + ko);  Bz1 = pack8(Whh + r1 * Hdim + 32 + ko);
    Bz2 = pack8(Whh + r1 * Hdim + 64 + ko);  Bz3 = pack8(Whh + r1 * Hdim + 96 + ko);
    Bn0 = pack8(Whh + r2 * Hdim + 0  + ko);  Bn1 = pack8(Whh + r2 * Hdim + 32 + ko);
    Bn2 = pack8(Whh + r2 * Hdim + 64 + ko);  Bn3 = pack8(Whh + r2 * Hdim + 96 + ko);

    // gate constants for this lane's column unit (valid on all lanes)
    const int ug = wave * 16 + m;
    const float wih_r = Wih[ug], wih_z = Wih[ug + 128], wih_n = Wih[ug + 256];
    const float bb_r = bih[ug]       + bhh[ug];
    const float bb_z = bih[ug + 128] + bhh[ug + 128];
    const float bi_n = bih[ug + 256];
    const float bh_n = bhh[ug + 256];
    const float bfc0 = bfc[0];
    const float wfc_u = Wfc[ug];             // f32 Wfc for the early fc partial

    // pre-scaled constants: fold log2e factors out of the per-step chain
    const float kNL2E = -1.44269504f;            // -log2(e)
    const float kP2L2E = 2.88539008f;            // 2*log2(e)
    const float wr_s  = kNL2E * wih_r;
    const float wz_s  = kNL2E * wih_z;
    const float wn_s  = kP2L2E * wih_n;
    const float bn_s  = kP2L2E * bi_n;
    // bias-seeded MFMA C operands (reg 0 is the one consumed)
    const f32x4 C_R = {bb_r, bb_r, bb_r, bb_r};
    const f32x4 C_Z = {bb_z, bb_z, bb_z, bb_z};
    const f32x4 C_N = {bh_n, bh_n, bh_n, bh_n};

    __syncthreads();                         // sm.x visible

    // ---- peeled t = 0: h = 0 => D = C-seed exactly; pure VALU ----
    float h_old;
    {
        float x0 = sm.x[0];
        float pr = wr_s * x0;
        float pz = wz_s * x0;
        float an = fmaf(wn_s, x0, bn_s);
        float r  = frcp_(1.0f + fexp2_(fmaf(kNL2E, bb_r, pr)));
        float z  = frcp_(1.0f + fexp2_(fmaf(kNL2E, bb_z, pz)));
        float rs = kP2L2E * r;
        float np = frcp_(fexp2_(fmaf(rs, bh_n, an)) + 1.0f);
        float w  = 1.0f - z;
        float hn = fmaf(-2.0f * w, np, w);   // hz = fma(z, 0, w) = w exactly
        h_old = hn;
        if (lane < 16) sm.h[1][ug] = (__fp16)hn;
        // fc partial for step 1 (from unrounded f32 hn)
        float pw = row16_sum(wfc_u * hn);
        if (lane == 0) sm.fcp[1][wave] = pw;
        // sm.xh[0] never consumed (out_pred uses xh[1..]; newin at i=0 is raw x)
    }
    __syncthreads();

#pragma unroll 1
    for (int t = 1; t < Tlen; ++t) {
        // A fragments + fc partials + xt: all LDS reads issued up front;
        // fcp/x are uniform-address (broadcast), latency overlaps A-reads.
        const float4* hp = (const float4*)sm.h[t & 1];
        hf8 A0 = bch8(hp[0 * 4 + q]);
        hf8 A1 = bch8(hp[1 * 4 + q]);
        hf8 A2 = bch8(hp[2 * 4 + q]);
        hf8 A3 = bch8(hp[3 * 4 + q]);
        const float4* fp = (const float4*)sm.fcp[t & 1];
        float4 pp0 = fp[0];
        float4 pp1 = fp[1];
        float xt = sm.x[t];

        // ---- 12 gate MFMAs (fc chain gone), bias pre-seeded via C ----
        f32x4 D0 = __builtin_amdgcn_mfma_f32_16x16x32_f16(A0, Br0, C_R, 0, 0, 0);
        MFMA(D0, A1, Br1); MFMA(D0, A2, Br2); MFMA(D0, A3, Br3);
        f32x4 D1 = __builtin_amdgcn_mfma_f32_16x16x32_f16(A0, Bz0, C_Z, 0, 0, 0);
        MFMA(D1, A1, Bz1); MFMA(D1, A2, Bz2); MFMA(D1, A3, Bz3);

        // xh from the previous step's partials: no MFMA dependency
        float xh  = (((pp0.x + pp0.y) + (pp0.z + pp0.w)) +
                     ((pp1.x + pp1.y) + (pp1.z + pp1.w))) + bfc0;
        float cur = (xt == 128.0f) ? xh : xt;
        float pr  = wr_s * cur;
        float pz  = wz_s * cur;
        float an  = fmaf(wn_s, cur, bn_s);

        f32x4 D2 = __builtin_amdgcn_mfma_f32_16x16x32_f16(A0, Bn0, C_N, 0, 0, 0);
        MFMA(D2, A1, Bn1); MFMA(D2, A2, Bn2); MFMA(D2, A3, Bn3);

        // gates: unpredicated on all 64 lanes (q-copies compute identical hn)
        float r   = frcp_(1.0f + fexp2_(fmaf(kNL2E, D0[0], pr)));
        float rs  = kP2L2E * r;
        float z   = frcp_(1.0f + fexp2_(fmaf(kNL2E, D1[0], pz)));
        float np  = frcp_(fexp2_(fmaf(rs, D2[0], an)) + 1.0f);  // n = 1 - 2*np
        float w   = 1.0f - z;
        float m2w = -2.0f * w;               // parallel to hz, off the chain
        float hz  = fmaf(z, h_old, w);
        float hn  = fmaf(m2w, np, hz);       // (1-z)*n + z*h
        h_old = hn;

        // next step's fc partial: DPP rotate-reduce over the m-group
        float pw = row16_sum(wfc_u * hn);

        if (lane < 16)  sm.h[(t + 1) & 1][ug] = (__fp16)hn;
        if (lane == 0)  sm.fcp[(t + 1) & 1][wave] = pw;
        if (tid == 0)   sm.xh[t] = xh;
        __syncthreads();
    }

    // bulk flush; cur reconstructed from pristine x + xh
    for (int i = tid; i < Tlen; i += 512) {
        float xv = sm.x[i];
        float cv = ((xv == 128.0f) && (i != 0)) ? sm.xh[i] : xv;
        out_newin[i * Bsz + b] = cv;
    }
    for (int i = tid; i < Tlen - 1; i += 512)
        out_pred[b * (Tlen - 1) + i] = sm.xh[i + 1];
}

extern "C" void kernel_launch(void* const* d_in, const int* in_sizes, int n_in,
                              void* d_out, int out_size, void* d_ws, size_t ws_size,
                              hipStream_t stream) {
    const float* x   = (const float*)d_in[0];
    const float* Wih = (const float*)d_in[1];
    const float* Whh = (const float*)d_in[2];
    const float* bih = (const float*)d_in[3];
    const float* bhh = (const float*)d_in[4];
    const float* Wfc = (const float*)d_in[5];
    const float* bfc = (const float*)d_in[6];

    float* out_newin = (float*)d_out;                 // [T*B] = 524288
    float* out_pred  = out_newin + Tlen * Bsz;        // [B*(T-1)] = 524032

    rnn_imp_kernel<<<Bsz, 512, 0, stream>>>(x, Wih, Whh, bih, bhh, Wfc, bfc,
                                            out_newin, out_pred);
}

// Round 5
// 894.537 us; speedup vs baseline: 1.1028x; 1.1028x over previous
//
#include <hip/hip_runtime.h>

#define Bsz  256
#define Tlen 2048
#define Hdim 128

typedef __fp16 hf2 __attribute__((ext_vector_type(2)));
typedef __fp16 hf8 __attribute__((ext_vector_type(8)));
typedef float  f32x4 __attribute__((ext_vector_type(4)));

// Raw-HW transcendentals (VOP1, ~1 ulp). R12-verified win.
__device__ __forceinline__ float fexp2_(float x) {
    float r; asm("v_exp_f32 %0, %1" : "=v"(r) : "v"(x)); return r;
}
__device__ __forceinline__ float frcp_(float x) {
    float r; asm("v_rcp_f32 %0, %1" : "=v"(r) : "v"(x)); return r;
}

// pack 8 consecutive f32 into a v8f16 MFMA fragment slice
__device__ __forceinline__ hf8 pack8(const float* p) {
    union { hf2 h2[4]; hf8 h8; } u;
    u.h2[0] = __builtin_amdgcn_cvt_pkrtz(p[0], p[1]);
    u.h2[1] = __builtin_amdgcn_cvt_pkrtz(p[2], p[3]);
    u.h2[2] = __builtin_amdgcn_cvt_pkrtz(p[4], p[5]);
    u.h2[3] = __builtin_amdgcn_cvt_pkrtz(p[6], p[7]);
    return u.h8;
}
__device__ __forceinline__ hf8 bch8(float4 v) { return __builtin_bit_cast(hf8, v); }

#define MFMA(D, A, B) D = __builtin_amdgcn_mfma_f32_16x16x32_f16(A, B, D, 0, 0, 0)

struct Smem {
    float  x[Tlen];       // staged input row
    float  xh[Tlen];      // staged xh outputs
    __fp16 h[2][Hdim];    // double-buffered hidden state (f16)
};

// grid = 256 blocks (1 batch row each), block = 512 threads (8 waves).
// R28 = R26 structure (the champion: 16 MFMA/wave/step, uniform-A,
// weights MFMA-only/AGPR-native, one barrier/step) + s_setprio wave
// antiphase. Session post-mortems:
//  - R24 (fc->VALU in-step):   -21%. Serial fma_mix+shuffle appendage.
//  - R25 (tail reorder):        flat.
//  - R26 (VALU diet):           flat. Per-lane VALU count not critical.
//  - R27 (fc one-step-early, 16->12 MFMA): -5%. MfmaUtil fell 48->34%
//    (407 cyc busy) but step GREW -> >=145 cyc of slack inside the MFMA
//    window; the DPP reduce on the tail cost ~60 cyc/step 1:1.
// Conclusion: step = fixed serial skeleton {barrier -> A ds_read(~120) ->
// MFMA window (slack) -> gate chain -> cvt+ds_write -> barrier resync};
// work-count changes don't move it. Last untested lever: the 2 waves/SIMD
// run IN PHASE (both burst MFMAs, then both run VALU tails). setprio(1)
// around the MFMA block makes the wave in its MFMA window outrank the
// wave in its tail -> antiphase -> tails hide under the other wave's
// MFMA window (T5 mechanism). If flat: declare roofline (pipe-sum:
// 48% MFMA + 38% VALU + 14% sync, each term empirically incompressible).
// Layouts (R18-R21 HW-verified): B: lane l reg j = W[tile*16+(l&15)]
// [c*32+(l>>4)*8+j]; D: col = lane&15, reg 0 valid on all lanes (uniform A).
__global__ __launch_bounds__(512, 2)
void rnn_imp_kernel(const float* __restrict__ x,     // [B, T] (I=1)
                    const float* __restrict__ Wih,   // [384]
                    const float* __restrict__ Whh,   // [384, 128] gate-major (r,z,n)
                    const float* __restrict__ bih,   // [384]
                    const float* __restrict__ bhh,   // [384]
                    const float* __restrict__ Wfc,   // [128]
                    const float* __restrict__ bfc,   // [1]
                    float* __restrict__ out_newin,   // [T, B]
                    float* __restrict__ out_pred)    // [B, T-1]
{
    __shared__ __align__(128) Smem sm;

    const int tid  = threadIdx.x;
    const int b    = blockIdx.x;
    const int wave = tid >> 6;
    const int lane = tid & 63;
    const int m    = lane & 15;      // B/D column = unit-in-tile
    const int q    = lane >> 4;      // k-subchunk

    // stage x row (coalesced)
    for (int i = tid; i < Tlen; i += 512) sm.x[i] = x[b * Tlen + i];

    // ---- B fragments: W^T tiles (consumed only by MFMA -> AGPR-native) ----
    const int r0 = wave * 16 + m;            // unit row, gate r
    const int r1 = r0 + 128;                 // gate z
    const int r2 = r0 + 256;                 // gate n
    const int ko = q * 8;
    hf8 Br0, Br1, Br2, Br3, Bz0, Bz1, Bz2, Bz3,
        Bn0, Bn1, Bn2, Bn3, Bf0, Bf1, Bf2, Bf3;
    Br0 = pack8(Whh + r0 * Hdim + 0  + ko);  Br1 = pack8(Whh + r0 * Hdim + 32 + ko);
    Br2 = pack8(Whh + r0 * Hdim + 64 + ko);  Br3 = pack8(Whh + r0 * Hdim + 96 + ko);
    Bz0 = pack8(Whh + r1 * Hdim + 0  + ko);  Bz1 = pack8(Whh + r1 * Hdim + 32 + ko);
    Bz2 = pack8(Whh + r1 * Hdim + 64 + ko);  Bz3 = pack8(Whh + r1 * Hdim + 96 + ko);
    Bn0 = pack8(Whh + r2 * Hdim + 0  + ko);  Bn1 = pack8(Whh + r2 * Hdim + 32 + ko);
    Bn2 = pack8(Whh + r2 * Hdim + 64 + ko);  Bn3 = pack8(Whh + r2 * Hdim + 96 + ko);
    // Wfc in ALL columns: every lane's D3 reg 0 = xp
    Bf0 = pack8(Wfc + 0  + ko);  Bf1 = pack8(Wfc + 32 + ko);
    Bf2 = pack8(Wfc + 64 + ko);  Bf3 = pack8(Wfc + 96 + ko);

    // gate constants for this lane's column unit (valid on all lanes)
    const int ug = wave * 16 + m;
    const float wih_r = Wih[ug], wih_z = Wih[ug + 128], wih_n = Wih[ug + 256];
    const float bb_r = bih[ug]       + bhh[ug];
    const float bb_z = bih[ug + 128] + bhh[ug + 128];
    const float bi_n = bih[ug + 256];
    const float bh_n = bhh[ug + 256];
    const float bfc0 = bfc[0];

    // pre-scaled constants: fold log2e factors out of the per-step chain
    const float kNL2E = -1.44269504f;            // -log2(e)
    const float kP2L2E = 2.88539008f;            // 2*log2(e)
    const float wr_s  = kNL2E * wih_r;
    const float wz_s  = kNL2E * wih_z;
    const float wn_s  = kP2L2E * wih_n;
    const float bn_s  = kP2L2E * bi_n;
    // bias-seeded MFMA C operands (reg 0 is the one consumed)
    const f32x4 C_R = {bb_r, bb_r, bb_r, bb_r};
    const f32x4 C_Z = {bb_z, bb_z, bb_z, bb_z};
    const f32x4 C_N = {bh_n, bh_n, bh_n, bh_n};
    const f32x4 C_F = {bfc0, bfc0, bfc0, bfc0};

    __syncthreads();                         // sm.x visible

    // ---- peeled t = 0: h = 0 => A = 0 => D = C-seed exactly; pure VALU ----
    float h_old;
    {
        float x0 = sm.x[0];
        float pr = wr_s * x0;
        float pz = wz_s * x0;
        float an = fmaf(wn_s, x0, bn_s);
        float r  = frcp_(1.0f + fexp2_(fmaf(kNL2E, bb_r, pr)));
        float z  = frcp_(1.0f + fexp2_(fmaf(kNL2E, bb_z, pz)));
        float rs = kP2L2E * r;
        float np = frcp_(fexp2_(fmaf(rs, bh_n, an)) + 1.0f);
        float w  = 1.0f - z;
        float hn = fmaf(-2.0f * w, np, w);   // hz = fma(z, 0, w) = w exactly
        h_old = hn;
        if (lane < 16) sm.h[1][ug] = (__fp16)hn;
        // sm.xh[0] never consumed (out_pred uses xh[1..]; newin at i=0 is raw x)
    }
    __syncthreads();

#pragma unroll 1
    for (int t = 1; t < Tlen; ++t) {
        // A fragments: every row = h (uniform-address broadcast reads)
        const float4* hp = (const float4*)sm.h[t & 1];
        hf8 A0 = bch8(hp[0 * 4 + q]);
        hf8 A1 = bch8(hp[1 * 4 + q]);
        hf8 A2 = bch8(hp[2 * 4 + q]);
        hf8 A3 = bch8(hp[3 * 4 + q]);

        // xt early: LDS latency hides under the MFMA block
        float xt = sm.x[t];

        // ---- MFMA window at raised priority: the wave in this region
        // outranks the wave in its VALU tail -> antiphase overlap ----
        __builtin_amdgcn_s_setprio(1);

        // phase 1: D3 (fc) and D0 (r-gate) chains complete first
        f32x4 D3 = __builtin_amdgcn_mfma_f32_16x16x32_f16(A0, Bf0, C_F, 0, 0, 0);
        f32x4 D0 = __builtin_amdgcn_mfma_f32_16x16x32_f16(A0, Br0, C_R, 0, 0, 0);
        MFMA(D3, A1, Bf1); MFMA(D0, A1, Br1);
        MFMA(D3, A2, Bf2); MFMA(D0, A2, Br2);
        MFMA(D3, A3, Bf3); MFMA(D0, A3, Br3);

        // phase 2: D1/D2 chains; cur + r-sigmoid hide under their issue
        f32x4 D1 = __builtin_amdgcn_mfma_f32_16x16x32_f16(A0, Bz0, C_Z, 0, 0, 0);
        f32x4 D2 = __builtin_amdgcn_mfma_f32_16x16x32_f16(A0, Bn0, C_N, 0, 0, 0);

        float xh  = D3[0];                   // bfc0 pre-seeded
        float cur = (xt == 128.0f) ? xh : xt;
        float pr  = wr_s * cur;
        float pz  = wz_s * cur;
        float an  = fmaf(wn_s, cur, bn_s);
        float r   = frcp_(1.0f + fexp2_(fmaf(kNL2E, D0[0], pr)));
        float rs  = kP2L2E * r;              // hoisted off the D2->hn path

        MFMA(D1, A1, Bz1); MFMA(D2, A1, Bn1);
        MFMA(D1, A2, Bz2); MFMA(D2, A2, Bn2);
        MFMA(D1, A3, Bz3); MFMA(D2, A3, Bn3);

        __builtin_amdgcn_s_setprio(0);       // tail runs at low priority

        // gates: unpredicated on all 64 lanes (q-copies compute identical hn)
        float z   = frcp_(1.0f + fexp2_(fmaf(kNL2E, D1[0], pz)));
        float np  = frcp_(fexp2_(fmaf(rs, D2[0], an)) + 1.0f);  // n = 1 - 2*np
        float w   = 1.0f - z;
        float m2w = -2.0f * w;               // parallel to hz, off the chain
        float hz  = fmaf(z, h_old, w);
        float hn  = fmaf(m2w, np, hz);       // (1-z)*n + z*h
        h_old = hn;

        if (lane < 16) sm.h[(t + 1) & 1][ug] = (__fp16)hn;
        if (tid == 0)  sm.xh[t] = xh;
        __syncthreads();
    }

    // bulk flush; cur reconstructed from pristine x + xh
    for (int i = tid; i < Tlen; i += 512) {
        float xv = sm.x[i];
        float cv = ((xv == 128.0f) && (i != 0)) ? sm.xh[i] : xv;
        out_newin[i * Bsz + b] = cv;
    }
    for (int i = tid; i < Tlen - 1; i += 512)
        out_pred[b * (Tlen - 1) + i] = sm.xh[i + 1];
}

extern "C" void kernel_launch(void* const* d_in, const int* in_sizes, int n_in,
                              void* d_out, int out_size, void* d_ws, size_t ws_size,
                              hipStream_t stream) {
    const float* x   = (const float*)d_in[0];
    const float* Wih = (const float*)d_in[1];
    const float* Whh = (const float*)d_in[2];
    const float* bih = (const float*)d_in[3];
    const float* bhh = (const float*)d_in[4];
    const float* Wfc = (const float*)d_in[5];
    const float* bfc = (const float*)d_in[6];

    float* out_newin = (float*)d_out;                 // [T*B] = 524288
    float* out_pred  = out_newin + Tlen * Bsz;        // [B*(T-1)] = 524032

    rnn_imp_kernel<<<Bsz, 512, 0, stream>>>(x, Wih, Whh, bih, bhh, Wfc, bfc,
                                            out_newin, out_pred);
}